// Round 8
// baseline (28.534 us; speedup 1.0000x reference)
//
#include <hip/hip_runtime.h>

// Problem constants (match reference)
#define BB 32
#define DD 32
#define HH 256
#define WW 256
#define KK 512

typedef __attribute__((ext_vector_type(8))) short bf16x8;
typedef __attribute__((ext_vector_type(4))) float f32x4;

// ws layout: u32[col][d], col = b*512 + k (0..16383), d = 0..31.
// word = bf16hi(v) in low 16 | bf16lo(v - hi) in high 16.  2 MiB total.

// ---------------------------------------------------------------------------
// Kernel A: gather, d-major thread mapping. gid = d*16384 + col, so each
// wave's 64 loads are 64 DISTINCT random (y,x) positions in one channel
// plane (max DRAM bank spread), instead of 2 positions x 32 planes at
// 256KB stride (potential per-column bank serialization).
// One packed 4B store per thread; ssq is reconstructed later in pairs.
// ---------------------------------------------------------------------------
__global__ __launch_bounds__(256) void tagloss_gather(
    const float* __restrict__ ebd, const int* __restrict__ kpts,
    unsigned* __restrict__ wsU, float* __restrict__ out) {
  int gid = blockIdx.x * 256 + threadIdx.x;   // 0 .. 524287
  if (gid == 0) out[0] = 0.f;
  int col = gid & 16383;                      // consecutive lanes -> cols
  int d   = gid >> 14;                        // one channel per wave
  int b   = col >> 9;

  int2 kp = ((const int2*)kpts)[col];         // (y, x) coalesced 8B
  float v = ebd[((size_t)(b * DD + d)) * (HH * WW) + (size_t)kp.x * WW + kp.y];

  unsigned u  = __float_as_uint(v);
  unsigned rn = u + 0x7FFFu + ((u >> 16) & 1u);        // RN-to-bf16
  float hif = __uint_as_float(rn & 0xFFFF0000u);
  float lof = v - hif;                                  // exact
  unsigned ul = __float_as_uint(lof);
  unsigned rl = ul + 0x7FFFu + ((ul >> 16) & 1u);

  wsU[col * DD + d] = (rn >> 16) | (rl & 0xFFFF0000u);  // hi | lo<<16
}

// ---------------------------------------------------------------------------
// Kernel B: reg-staged unpack of packed ws -> same physical LDS layout as
// the validated R5/R7 kernel (hi plane 32KB, lo plane 32KB, chunk swizzle
// phys = pc ^ ((col>>1)&3)), via v_perm_b32. ssq partials computed from
// (hi+lo)^2 during staging (err ~2^-17), finalized after a barrier.
// Compute phase unchanged: balanced triangle k-tile pair {p, 31-p},
// 3 chained mfma_f32_16x16x32_bf16 per job, sigmoid-MSE epilogue.
// ---------------------------------------------------------------------------
__global__ __launch_bounds__(256, 2) void tagloss_pairs(
    const char* __restrict__ ws, const int* __restrict__ tags,
    float* __restrict__ out) {
  __shared__ __align__(16) char P[65536];   // [plane 32KB][col*64 + phys*16]
  __shared__ float ssqP[2048];              // per-(col,pc) partials
  __shared__ float ssqL[KK];
  __shared__ int   tagL[KK];
  __shared__ float red[4];

  const int tid = threadIdx.x;
  const int b = blockIdx.y;
  const int p = blockIdx.x;                 // 0..15 -> k-tile pair {p, 31-p}

  // ---- stage: 2048 (col,pc) slots; each -> hi 16B + lo 16B + ssq partial --
  const char* wsb = ws + (size_t)b * 65536; // 512 cols * 128B
#pragma unroll
  for (int i = 0; i < 8; ++i) {
    int slot = tid + i * 256;               // 0..2047 = col*4 + pc
    int col = slot >> 2, pc = slot & 3;
    const uint4* g = (const uint4*)(wsb + col * 128 + pc * 32);
    uint4 ga = g[0], gb = g[1];             // 8 packed words, d = pc*8 ..

    unsigned h0 = __builtin_amdgcn_perm(ga.y, ga.x, 0x05040100u);
    unsigned h1 = __builtin_amdgcn_perm(ga.w, ga.z, 0x05040100u);
    unsigned h2 = __builtin_amdgcn_perm(gb.y, gb.x, 0x05040100u);
    unsigned h3 = __builtin_amdgcn_perm(gb.w, gb.z, 0x05040100u);
    unsigned l0 = __builtin_amdgcn_perm(ga.y, ga.x, 0x07060302u);
    unsigned l1 = __builtin_amdgcn_perm(ga.w, ga.z, 0x07060302u);
    unsigned l2 = __builtin_amdgcn_perm(gb.y, gb.x, 0x07060302u);
    unsigned l3 = __builtin_amdgcn_perm(gb.w, gb.z, 0x07060302u);

    int phys = pc ^ ((col >> 1) & 3);
    *(uint4*)(P + col * 64 + phys * 16)         = make_uint4(h0, h1, h2, h3);
    *(uint4*)(P + 32768 + col * 64 + phys * 16) = make_uint4(l0, l1, l2, l3);

    float s = 0.f;
    unsigned wv[8] = {ga.x, ga.y, ga.z, ga.w, gb.x, gb.y, gb.z, gb.w};
#pragma unroll
    for (int q = 0; q < 8; ++q) {
      float hf = __uint_as_float(wv[q] << 16);
      float lf = __uint_as_float(wv[q] & 0xFFFF0000u);
      float vf = hf + lf;
      s = fmaf(vf, vf, s);
    }
    ssqP[slot] = s;
  }
  tagL[tid]       = tags[b * KK + tid];
  tagL[tid + 256] = tags[b * KK + tid + 256];
  __syncthreads();

  // ---- finalize ssq: ssqL[c] = sum of 4 pc-partials ----
#pragma unroll
  for (int i = 0; i < 2; ++i) {
    int c = tid + i * 256;
    f32x4 q = *(const f32x4*)&ssqP[c * 4];
    ssqL[c] = (q[0] + q[1]) + (q[2] + q[3]);
  }
  __syncthreads();

  // ---- compute (identical to validated R5/R7) ----
  const int w = tid >> 6, lane = tid & 63;
  const int lx = lane & 15, dchunk = lane >> 4;

  const int i0 = p, i1 = 31 - p;            // the two k-tiles (16 rows each)
  const int lim = 32 - i0;                  // job count of row i0

  const int colA0 = i0 * 16 + lx;
  const int colA1 = i1 * 16 + lx;
  const int swzA0 = ((dchunk ^ ((colA0 >> 1) & 3)) * 16);
  const int swzA1 = ((dchunk ^ ((colA1 >> 1) & 3)) * 16);
  bf16x8 a0hi = *(const bf16x8*)(P + colA0 * 64 + swzA0);
  bf16x8 a0lo = *(const bf16x8*)(P + 32768 + colA0 * 64 + swzA0);
  bf16x8 a1hi = *(const bf16x8*)(P + colA1 * 64 + swzA1);
  bf16x8 a1lo = *(const bf16x8*)(P + 32768 + colA1 * 64 + swzA1);

  const int krow0 = i0 * 16 + dchunk * 4;
  const int krow1 = i1 * 16 + dchunk * 4;
  float ssqk0[4], ssqk1[4];
  int   tagk0[4], tagk1[4];
#pragma unroll
  for (int r = 0; r < 4; ++r) {
    ssqk0[r] = ssqL[krow0 + r]; tagk0[r] = tagL[krow0 + r];
    ssqk1[r] = ssqL[krow1 + r]; tagk1[r] = tagL[krow1 + r];
  }

  float loss = 0.f;

#define JOB(AHI, ALO, SSQK, TAGK, KT, JT)                                      \
  {                                                                            \
    const int colB = (JT) * 16 + lx;                                           \
    const int swzB = ((dchunk ^ ((colB >> 1) & 3)) * 16);                      \
    bf16x8 bhi = *(const bf16x8*)(P + colB * 64 + swzB);                       \
    bf16x8 blo = *(const bf16x8*)(P + 32768 + colB * 64 + swzB);               \
    f32x4 acc = {0.f, 0.f, 0.f, 0.f};                                          \
    acc = __builtin_amdgcn_mfma_f32_16x16x32_bf16(ALO, bhi, acc, 0, 0, 0);     \
    acc = __builtin_amdgcn_mfma_f32_16x16x32_bf16(AHI, blo, acc, 0, 0, 0);     \
    acc = __builtin_amdgcn_mfma_f32_16x16x32_bf16(AHI, bhi, acc, 0, 0, 0);     \
    float ssql = ssqL[colB];                                                   \
    int   tagl = tagL[colB];                                                   \
    float jobLoss = 0.f;                                                       \
    _Pragma("unroll")                                                          \
    for (int r = 0; r < 4; ++r) {                                              \
      float expo = (SSQK[r] + ssql - 2.f * acc[r]) * 0.03125f;                 \
      float ps = 2.f * __builtin_amdgcn_rcpf(1.f + __expf(expo));              \
      float t = (TAGK[r] == tagl) ? 1.f : 0.f;                                 \
      float df = t - ps;                                                       \
      jobLoss = fmaf(df, df, jobLoss);                                         \
    }                                                                          \
    float wtf = ((KT) == (JT)) ? 1.f : 2.f;                                    \
    loss = fmaf(jobLoss, wtf, loss);                                           \
  }

  for (int t = w; t < lim; t += 4) JOB(a0hi, a0lo, ssqk0, tagk0, i0, i0 + t);
  {
    int m0 = (lim > w) ? ((lim - w + 3) >> 2) : 0;
    for (int t = w + 4 * m0; t < 33; t += 4)
      JOB(a1hi, a1lo, ssqk1, tagk1, i1, i1 + (t - lim));
  }
#undef JOB

  // ---- reduce ----
#pragma unroll
  for (int off = 32; off > 0; off >>= 1) loss += __shfl_down(loss, off);
  if (lane == 0) red[w] = loss;
  __syncthreads();
  if (tid == 0)
    atomicAdd(out, (red[0] + red[1] + red[2] + red[3]) * (1.f / 8388608.f));
}

extern "C" void kernel_launch(void* const* d_in, const int* in_sizes, int n_in,
                              void* d_out, int out_size, void* d_ws, size_t ws_size,
                              hipStream_t stream) {
  const float* ebd  = (const float*)d_in[0];
  const int*   kpts = (const int*)d_in[1];
  const int*   tags = (const int*)d_in[2];
  float* out = (float*)d_out;

  tagloss_gather<<<(BB * KK * DD) / 256, 256, 0, stream>>>(
      ebd, kpts, (unsigned*)d_ws, out);
  tagloss_pairs<<<dim3(16, BB), 256, 0, stream>>>((const char*)d_ws, tags, out);
}